// Round 9
// baseline (172.667 us; speedup 1.0000x reference)
//
#include <hip/hip_runtime.h>

// ---------------------------------------------------------------------------
// CNN + FC + 2x GraphSAGE, collapsed to scalar fields (GNN part is linear).
// fc2 + both SAGE layers folded into 86 coefficients (k_scan).
// k_mlp: 4-wave blocks, 256 rows/block in 4 sub-tiles of 64 rows; sub-tiles
// double-buffered in LDS via global_load_lds (width 16) with counted
// s_waitcnt vmcnt(7) + raw s_barrier so the prefetch stays in flight across
// barriers (T3/T4). Compute core = round-8's verified 4-thread/row scheme.
// Aggregation via per-call CSR + register-accumulating gather (no f32 atomics).
// ---------------------------------------------------------------------------

#define BUF0 0
#define BUF1 6912
#define WB   13824   // weights: conv 480 | bias 20 | f1w 660 (stride 33) | f1b 20 | coef 86
#define FEAT 15090   // 64 x 33
#define HL   17202   // 64 x 25
#define LDS_TOT 18802

__global__ void k_zero(int* __restrict__ cnt, int N) {
  int n = blockIdx.x * blockDim.x + threadIdx.x;
  if (n < N) cnt[n] = 0;
}

__global__ void k_count(const int* __restrict__ dst, int E, int* __restrict__ cnt) {
  int e = blockIdx.x * blockDim.x + threadIdx.x;
  if (e < E) atomicAdd(&cnt[dst[e]], 1);
}

// single block: weight folding (threads 0..20) + exclusive scan of cnt
__global__ __launch_bounds__(1024) void k_scan(
    const int* __restrict__ cnt, int N,
    int* __restrict__ row_ptr, int* __restrict__ cursor,
    const float* __restrict__ f2w, const float* __restrict__ f2b,
    const float* __restrict__ g1_wl, const float* __restrict__ g1_bl,
    const float* __restrict__ g1_wr, const float* __restrict__ g2_wl,
    const float* __restrict__ g2_wr, float* __restrict__ coef) {
  int t = threadIdx.x;

  if (t < 21) {
    float a[5], r1[5], c[5], r2[5];
#pragma unroll
    for (int k = 0; k < 5; ++k) { a[k] = 0.f; r1[k] = 0.f; c[k] = 0.f; r2[k] = 0.f; }
#pragma unroll
    for (int j = 0; j < 20; ++j) {
      float wl2 = g2_wl[j], wr2 = g2_wr[j];
#pragma unroll
      for (int k = 0; k < 5; ++k) {
        float wl1 = g1_wl[j * 5 + k], wr1 = g1_wr[j * 5 + k];
        a[k]  = fmaf(wl2, wl1, a[k]);
        r1[k] = fmaf(wr2, wl1, r1[k]);
        c[k]  = fmaf(wl2, wr1, c[k]);
        r2[k] = fmaf(wr2, wr1, r2[k]);
      }
    }
    if (t < 20) {
      float A = 0.f, R1 = 0.f, C = 0.f, R2 = 0.f;
#pragma unroll
      for (int k = 0; k < 5; ++k) {
        float w = f2w[k * 20 + t];
        A  = fmaf(a[k],  w, A);
        R1 = fmaf(r1[k], w, R1);
        C  = fmaf(c[k],  w, C);
        R2 = fmaf(r2[k], w, R2);
      }
      coef[t] = A; coef[20 + t] = R1; coef[40 + t] = C; coef[60 + t] = R2;
    } else {
      float ca = 0.f, cr1 = 0.f, cc = 0.f, cr2 = 0.f;
#pragma unroll
      for (int k = 0; k < 5; ++k) {
        float b = f2b[k];
        ca = fmaf(a[k], b, ca);  cr1 = fmaf(r1[k], b, cr1);
        cc = fmaf(c[k], b, cc);  cr2 = fmaf(r2[k], b, cr2);
      }
      coef[80] = ca; coef[81] = cr1; coef[82] = cc; coef[83] = cr2;
      float kb1 = 0.f, kb2 = 0.f;
#pragma unroll
      for (int j = 0; j < 20; ++j) {
        kb1 = fmaf(g2_wl[j], g1_bl[j], kb1);
        kb2 = fmaf(g2_wr[j], g1_bl[j], kb2);
      }
      coef[84] = kb1; coef[85] = kb2;
    }
  }

  __shared__ int part[1024];
  int chunk = (N + 1023) / 1024;
  int s0 = t * chunk, s1 = min(N, s0 + chunk);
  int sum = 0;
  for (int i = s0; i < s1; ++i) sum += cnt[i];
  part[t] = sum;
  __syncthreads();
  for (int off = 1; off < 1024; off <<= 1) {
    int v = (t >= off) ? part[t - off] : 0;
    __syncthreads();
    part[t] += v;
    __syncthreads();
  }
  int run = (t == 0) ? 0 : part[t - 1];
  for (int i = s0; i < s1; ++i) {
    row_ptr[i] = run; cursor[i] = run;
    run += cnt[i];
  }
  if (s1 == N) row_ptr[N] = run;
}

__global__ void k_scatter(const int* __restrict__ src, const int* __restrict__ dst, int E,
                          int* __restrict__ cursor, int* __restrict__ adj) {
  int e = blockIdx.x * blockDim.x + threadIdx.x;
  if (e < E) {
    int pos = atomicAdd(&cursor[dst[e]], 1);
    adj[pos] = src[e];
  }
}

// Stage one 64-row sub-tile (1728 float4 chunks) into LDS at lbuf.
// Wave-uniform LDS slot base s*1024B; HW adds lane*16. Global side is
// per-lane: chunk c = s*64+lane -> row c/27, part c%27 (432B-contiguous runs).
// Exactly 7 instructions per wave (slot 26 duplicated by waves 2,3: benign).
__device__ __forceinline__ void stage_tile(const float* __restrict__ x,
                                           float* lbuf, int row0, int rows,
                                           int w, int lane) {
#pragma unroll
  for (int j = 0; j < 7; ++j) {
    int s = j * 4 + w; if (s > 26) s = 26;
    int c = s * 64 + lane;
    int dr = c / 27, part = c - dr * 27;
    int row = row0 + dr; if (row >= rows) row = rows - 1;
    const float* src = x + (size_t)row * 108 + part * 4;
    __builtin_amdgcn_global_load_lds(
        (const __attribute__((address_space(1))) unsigned int*)src,
        (__attribute__((address_space(3))) unsigned int*)(lbuf + s * 256),
        16, 0, 0);
  }
}

__global__ __launch_bounds__(256) void k_mlp(
    const float* __restrict__ x,
    const float* __restrict__ w_t, const float* __restrict__ b_t,
    const float* __restrict__ w_r, const float* __restrict__ b_r,
    const float* __restrict__ w_tp, const float* __restrict__ b_tp,
    const float* __restrict__ w_ssr, const float* __restrict__ b_ssr,
    const float* __restrict__ f1w, const float* __restrict__ f1b,
    const float* __restrict__ coef,
    float2* __restrict__ F1v, float2* __restrict__ F2v, int N, int rows) {
  __shared__ float S[LDS_TOT];
  const int t = threadIdx.x;
  const int w = t >> 6, lane = t & 63;
  const int q = t & 3, r = t >> 2;
  const int base = blockIdx.x * 256;

  // prologue: DMA sub-tile 0, stage weights under it
  stage_tile(x, S + BUF0, base, rows, w, lane);

  if (t < 120) {
    S[WB + t] = w_t[t]; S[WB + 120 + t] = w_r[t];
    S[WB + 240 + t] = w_tp[t]; S[WB + 360 + t] = w_ssr[t];
  }
  if (t < 5) {
    S[WB + 480 + t] = b_t[t]; S[WB + 485 + t] = b_r[t];
    S[WB + 490 + t] = b_tp[t]; S[WB + 495 + t] = b_ssr[t];
  }
  for (int i = t; i < 640; i += 256) {
    int o = i >> 5, k = i & 31;
    S[WB + 500 + o * 33 + k] = f1w[i];
  }
  if (t < 20) S[WB + 1160 + t] = f1b[t];
  if (t >= 128 && t < 128 + 86) S[WB + 1180 + t - 128] = coef[t - 128];

  for (int st = 0; st < 4; ++st) {
    float* cur = S + ((st & 1) ? BUF1 : BUF0);
    if (st < 3) {
      stage_tile(x, S + ((st & 1) ? BUF0 : BUF1), base + (st + 1) * 64, rows, w, lane);
      asm volatile("s_waitcnt vmcnt(7) lgkmcnt(0)" ::: "memory");
    } else {
      asm volatile("s_waitcnt vmcnt(0) lgkmcnt(0)" ::: "memory");
    }
    __builtin_amdgcn_sched_barrier(0);
    __builtin_amdgcn_s_barrier();
    __builtin_amdgcn_sched_barrier(0);

    int rr = base + st * 64 + r;
    bool live = rr < rows;
    const float* xr = cur + r * 108;

    // conv branch q from LDS row
    float acc[5];
#pragma unroll
    for (int o = 0; o < 5; ++o) acc[o] = S[WB + 480 + q * 5 + o];
#pragma unroll
    for (int i = 0; i < 6; ++i) {
      float4 w4 = *reinterpret_cast<const float4*>(xr + 12 + 24 * q + 4 * i);
#pragma unroll
      for (int o = 0; o < 5; ++o) {
        const int wb = WB + q * 120 + o * 24 + 4 * i;
        acc[o] = fmaf(w4.x, S[wb + 0], acc[o]);
        acc[o] = fmaf(w4.y, S[wb + 1], acc[o]);
        acc[o] = fmaf(w4.z, S[wb + 2], acc[o]);
        acc[o] = fmaf(w4.w, S[wb + 3], acc[o]);
      }
    }
    float* fr = &S[FEAT + r * 33];
    if (q > 0) {
      float4 pv = *reinterpret_cast<const float4*>(xr + 4 * (q - 1));
      fr[4 * (q - 1) + 0] = pv.x; fr[4 * (q - 1) + 1] = pv.y;
      fr[4 * (q - 1) + 2] = pv.z; fr[4 * (q - 1) + 3] = pv.w;
    }
#pragma unroll
    for (int o = 0; o < 5; ++o) fr[12 + q * 5 + o] = fmaxf(acc[o], 0.f);
    asm volatile("s_waitcnt lgkmcnt(0)" ::: "memory");
    __builtin_amdgcn_s_barrier();
    __builtin_amdgcn_sched_barrier(0);

    // fc1: outputs o = q*5+j
    float a2[5];
#pragma unroll
    for (int j = 0; j < 5; ++j) a2[j] = S[WB + 1160 + q * 5 + j];
#pragma unroll
    for (int i = 0; i < 32; ++i) {
      float f = fr[i];
#pragma unroll
      for (int j = 0; j < 5; ++j)
        a2[j] = fmaf(f, S[WB + 500 + (q * 5 + j) * 33 + i], a2[j]);
    }
    float* hr = &S[HL + r * 25];
#pragma unroll
    for (int j = 0; j < 5; ++j) hr[q * 5 + j] = fmaxf(a2[j], 0.f);
    asm volatile("s_waitcnt lgkmcnt(0)" ::: "memory");
    __builtin_amdgcn_s_barrier();
    __builtin_amdgcn_sched_barrier(0);

    // folded fc2+SAGE: thread computes scalar field q
    float s = S[WB + 1180 + 80 + q];
#pragma unroll
    for (int i = 0; i < 20; ++i) s = fmaf(hr[i], S[WB + 1180 + q * 20 + i], s);
    hr[20 + q] = s;
    asm volatile("s_waitcnt lgkmcnt(0)" ::: "memory");
    __builtin_amdgcn_s_barrier();
    __builtin_amdgcn_sched_barrier(0);

    if (q == 0 && live) {
      int b = rr / N;
      int n = rr - b * N;
      F1v[n * 16 + b] = make_float2(hr[20], hr[21]);
      F2v[n * 16 + b] = make_float2(hr[22], hr[23]);
    }
  }
}

// 16 lanes per node (one per batch). Adjacency: coalesced 16-chunk load +
// __shfl broadcast. Gather F1v[s*16+b] = 128B contiguous per group.
__global__ void k_agg1(const int* __restrict__ row_ptr, const int* __restrict__ adj,
                       const float2* __restrict__ F1v, const float2* __restrict__ F2v,
                       float* __restrict__ W, float* __restrict__ V, int N) {
  int t = blockIdx.x * blockDim.x + threadIdx.x;
  int g = t >> 4, b = t & 15;
  if (g >= N) return;
  int beg = row_ptr[g], end = row_ptr[g + 1];
  float sa = 0.f, sb = 0.f;
  for (int c = beg; c < end; c += 16) {
    int idx = c + b;
    int a = adj[idx < end ? idx : end - 1];
    int m = min(16, end - c);
    for (int k = 0; k < m; ++k) {
      int s = __shfl(a, k, 16);
      float2 f = F1v[s * 16 + b];
      sa += f.x; sb += f.y;
    }
  }
  float inv = 1.0f / fmaxf((float)(end - beg), 1.0f);
  float2 f2 = F2v[t];
  W[t] = sa * inv + f2.x;
  V[t] = sb * inv;
}

// second gather over W, fused with the final epilogue; LDS transpose so the
// out[b*N+n] write is coalesced per plane.
__global__ __launch_bounds__(256) void k_agg2(
    const int* __restrict__ row_ptr, const int* __restrict__ adj,
    const float* __restrict__ W, const float* __restrict__ V,
    const float2* __restrict__ F2v, const float* __restrict__ coef,
    const float* __restrict__ g2_bl, float* __restrict__ out, int N) {
  __shared__ float tile[16][17];
  int t = blockIdx.x * 256 + threadIdx.x;
  int g = t >> 4, b = t & 15;
  float r = 0.f;
  if (g < N) {
    int beg = row_ptr[g], end = row_ptr[g + 1];
    float sw = 0.f;
    for (int c = beg; c < end; c += 16) {
      int idx = c + b;
      int a = adj[idx < end ? idx : end - 1];
      int m = min(16, end - c);
      for (int k = 0; k < m; ++k) {
        int s = __shfl(a, k, 16);
        sw += W[s * 16 + b];
      }
    }
    int deg = end - beg;
    float inv = 1.0f / fmaxf((float)deg, 1.0f);
    float chi = deg > 0 ? 1.f : 0.f;
    r = sw * inv + V[t] + F2v[t].y + coef[84] * chi + coef[85] + g2_bl[0];
  }
  int gl = (threadIdx.x >> 4);
  tile[b][gl] = r;
  __syncthreads();
  int b2 = threadIdx.x >> 4;
  int gl2 = threadIdx.x & 15;
  int n2 = blockIdx.x * 16 + gl2;
  if (n2 < N) out[(size_t)b2 * N + n2] = tile[b2][gl2];
}

extern "C" void kernel_launch(void* const* d_in, const int* in_sizes, int n_in,
                              void* d_out, int out_size, void* d_ws, size_t ws_size,
                              hipStream_t stream) {
  const float* x     = (const float*)d_in[0];
  const int*   ei    = (const int*)d_in[1];
  const float* w_t   = (const float*)d_in[2];
  const float* b_t   = (const float*)d_in[3];
  const float* w_r   = (const float*)d_in[4];
  const float* b_r   = (const float*)d_in[5];
  const float* w_tp  = (const float*)d_in[6];
  const float* b_tp  = (const float*)d_in[7];
  const float* w_ssr = (const float*)d_in[8];
  const float* b_ssr = (const float*)d_in[9];
  const float* f1w   = (const float*)d_in[10];
  const float* f1b   = (const float*)d_in[11];
  const float* f2w   = (const float*)d_in[12];
  const float* f2b   = (const float*)d_in[13];
  const float* g1_wl = (const float*)d_in[14];
  const float* g1_bl = (const float*)d_in[15];
  const float* g1_wr = (const float*)d_in[16];
  const float* g2_wl = (const float*)d_in[17];
  const float* g2_bl = (const float*)d_in[18];
  const float* g2_wr = (const float*)d_in[19];
  float* out = (float*)d_out;

  const int E = in_sizes[1] / 2;
  const int N = out_size / 16;   // B = 16
  const int rows = out_size;     // N * B
  const int* src = ei;
  const int* dst = ei + E;

  // workspace
  float* ws  = (float*)d_ws;
  float2* F1v = (float2*)ws;                    // 16N float2
  float2* F2v = F1v + (size_t)16 * N;           // 16N float2
  float*  W   = (float*)(F2v + (size_t)16 * N); // 16N f32
  float*  V   = W + (size_t)16 * N;             // 16N f32
  float*  coef = V + (size_t)16 * N;            // 86
  int* cnt     = (int*)(coef + 128);            // N
  int* row_ptr = cnt + N;                       // N+1
  int* cursor  = row_ptr + N + 1;               // N
  int* adj     = cursor + N;                    // E

  int nb16 = (N * 16 + 255) / 256;

  k_zero<<<(N + 255) / 256, 256, 0, stream>>>(cnt, N);
  k_count<<<(E + 255) / 256, 256, 0, stream>>>(dst, E, cnt);
  k_scan<<<1, 1024, 0, stream>>>(cnt, N, row_ptr, cursor,
                                 f2w, f2b, g1_wl, g1_bl, g1_wr, g2_wl, g2_wr, coef);
  k_scatter<<<(E + 255) / 256, 256, 0, stream>>>(src, dst, E, cursor, adj);
  k_mlp<<<(rows + 255) / 256, 256, 0, stream>>>(
      x, w_t, b_t, w_r, b_r, w_tp, b_tp, w_ssr, b_ssr,
      f1w, f1b, coef, F1v, F2v, N, rows);
  k_agg1<<<nb16, 256, 0, stream>>>(row_ptr, adj, F1v, F2v, W, V, N);
  k_agg2<<<nb16, 256, 0, stream>>>(row_ptr, adj, W, V, F2v, coef, g2_bl, out, N);
}

// Round 10
// 141.948 us; speedup vs baseline: 1.2164x; 1.2164x over previous
//
#include <hip/hip_runtime.h>

// ---------------------------------------------------------------------------
// CNN + FC + 2x GraphSAGE, collapsed to scalar fields (GNN part is linear).
// fc2 + both SAGE layers folded into 86 coefficients (k_scan).
// k_mlp: block = 64 rows x 4 threads/row. Load phase: thread t loads chunk
// i*256+t -> each wave instruction reads 1024B CONTIGUOUS (16 lines, fully
// consumed) and ds_write_b128 into PAD=132 LDS rows (16B-aligned, even bank
// spread). Compute: conv branch q per thread, fc1, coef partials reduced via
// __shfl_xor(width 4). 2 barriers, 45KB LDS -> 3 blocks/CU.
// Aggregation via per-call CSR + register-accumulating gather (no f32 atomics),
// inner loop manually 4x unrolled for load-latency hiding.
// ---------------------------------------------------------------------------

#define PAD 132
#define XB  0              // 64*132 = 8448 floats
#define CV  8448           // conv-out: 64 rows x 24 (20 used)
#define WB  9984           // conv w 480 | conv b 20 | f1w 660 (stride 33) | f1b 20 | coef 86
#define LDS_TOT 11250      // floats (45000 B)

__global__ void k_zero(int* __restrict__ cnt, int N) {
  int n = blockIdx.x * blockDim.x + threadIdx.x;
  if (n < N) cnt[n] = 0;
}

__global__ void k_count(const int* __restrict__ dst, int E, int* __restrict__ cnt) {
  int e = blockIdx.x * blockDim.x + threadIdx.x;
  if (e < E) atomicAdd(&cnt[dst[e]], 1);
}

// single block: weight folding (threads 0..20) + exclusive scan of cnt
__global__ __launch_bounds__(1024) void k_scan(
    const int* __restrict__ cnt, int N,
    int* __restrict__ row_ptr, int* __restrict__ cursor,
    const float* __restrict__ f2w, const float* __restrict__ f2b,
    const float* __restrict__ g1_wl, const float* __restrict__ g1_bl,
    const float* __restrict__ g1_wr, const float* __restrict__ g2_wl,
    const float* __restrict__ g2_wr, float* __restrict__ coef) {
  int t = threadIdx.x;

  if (t < 21) {
    float a[5], r1[5], c[5], r2[5];
#pragma unroll
    for (int k = 0; k < 5; ++k) { a[k] = 0.f; r1[k] = 0.f; c[k] = 0.f; r2[k] = 0.f; }
#pragma unroll
    for (int j = 0; j < 20; ++j) {
      float wl2 = g2_wl[j], wr2 = g2_wr[j];
#pragma unroll
      for (int k = 0; k < 5; ++k) {
        float wl1 = g1_wl[j * 5 + k], wr1 = g1_wr[j * 5 + k];
        a[k]  = fmaf(wl2, wl1, a[k]);
        r1[k] = fmaf(wr2, wl1, r1[k]);
        c[k]  = fmaf(wl2, wr1, c[k]);
        r2[k] = fmaf(wr2, wr1, r2[k]);
      }
    }
    if (t < 20) {
      float A = 0.f, R1 = 0.f, C = 0.f, R2 = 0.f;
#pragma unroll
      for (int k = 0; k < 5; ++k) {
        float w = f2w[k * 20 + t];
        A  = fmaf(a[k],  w, A);
        R1 = fmaf(r1[k], w, R1);
        C  = fmaf(c[k],  w, C);
        R2 = fmaf(r2[k], w, R2);
      }
      coef[t] = A; coef[20 + t] = R1; coef[40 + t] = C; coef[60 + t] = R2;
    } else {
      float ca = 0.f, cr1 = 0.f, cc = 0.f, cr2 = 0.f;
#pragma unroll
      for (int k = 0; k < 5; ++k) {
        float b = f2b[k];
        ca = fmaf(a[k], b, ca);  cr1 = fmaf(r1[k], b, cr1);
        cc = fmaf(c[k], b, cc);  cr2 = fmaf(r2[k], b, cr2);
      }
      coef[80] = ca; coef[81] = cr1; coef[82] = cc; coef[83] = cr2;
      float kb1 = 0.f, kb2 = 0.f;
#pragma unroll
      for (int j = 0; j < 20; ++j) {
        kb1 = fmaf(g2_wl[j], g1_bl[j], kb1);
        kb2 = fmaf(g2_wr[j], g1_bl[j], kb2);
      }
      coef[84] = kb1; coef[85] = kb2;
    }
  }

  __shared__ int part[1024];
  int chunk = (N + 1023) / 1024;
  int s0 = t * chunk, s1 = min(N, s0 + chunk);
  int sum = 0;
  for (int i = s0; i < s1; ++i) sum += cnt[i];
  part[t] = sum;
  __syncthreads();
  for (int off = 1; off < 1024; off <<= 1) {
    int v = (t >= off) ? part[t - off] : 0;
    __syncthreads();
    part[t] += v;
    __syncthreads();
  }
  int run = (t == 0) ? 0 : part[t - 1];
  for (int i = s0; i < s1; ++i) {
    row_ptr[i] = run; cursor[i] = run;
    run += cnt[i];
  }
  if (s1 == N) row_ptr[N] = run;
}

__global__ void k_scatter(const int* __restrict__ src, const int* __restrict__ dst, int E,
                          int* __restrict__ cursor, int* __restrict__ adj) {
  int e = blockIdx.x * blockDim.x + threadIdx.x;
  if (e < E) {
    int pos = atomicAdd(&cursor[dst[e]], 1);
    adj[pos] = src[e];
  }
}

// block = 64 rows (grid 5000 exact), 256 threads.
__global__ __launch_bounds__(256) void k_mlp(
    const float* __restrict__ x,
    const float* __restrict__ w_t, const float* __restrict__ b_t,
    const float* __restrict__ w_r, const float* __restrict__ b_r,
    const float* __restrict__ w_tp, const float* __restrict__ b_tp,
    const float* __restrict__ w_ssr, const float* __restrict__ b_ssr,
    const float* __restrict__ f1w, const float* __restrict__ f1b,
    const float* __restrict__ coef,
    float2* __restrict__ F1v, float2* __restrict__ F2v, int N) {
  __shared__ float S[LDS_TOT];
  const int t = threadIdx.x;
  const int q = t & 3, r = t >> 2;
  const size_t base = (size_t)blockIdx.x * 64;

  // ---- load phase: 7 contiguous-1KB-per-wave instructions ----
  // chunk c = i*256+t of the block's 64*108-float slab; dest row c/27, part c%27.
  float4 ld[7];
  const float4* xs = reinterpret_cast<const float4*>(x + base * 108);
#pragma unroll
  for (int i = 0; i < 7; ++i) {
    int c = i * 256 + t;
    ld[i] = xs[c < 1728 ? c : 1727];
  }

  // ---- stage weights + coefs (overlaps the x loads) ----
  if (t < 120) {
    S[WB + t] = w_t[t]; S[WB + 120 + t] = w_r[t];
    S[WB + 240 + t] = w_tp[t]; S[WB + 360 + t] = w_ssr[t];
  }
  if (t < 5) {
    S[WB + 480 + t] = b_t[t]; S[WB + 485 + t] = b_r[t];
    S[WB + 490 + t] = b_tp[t]; S[WB + 495 + t] = b_ssr[t];
  }
  for (int i = t; i < 640; i += 256) {
    int o = i >> 5, k = i & 31;
    S[WB + 500 + o * 33 + k] = f1w[i];
  }
  if (t < 20) S[WB + 1160 + t] = f1b[t];
  if (t >= 128 && t < 128 + 86) S[WB + 1180 + t - 128] = coef[t - 128];

  // ---- scatter chunks into padded LDS rows ----
#pragma unroll
  for (int i = 0; i < 7; ++i) {
    int c = i * 256 + t;
    if (c < 1728) {
      int row = c / 27, part = c - row * 27;
      *reinterpret_cast<float4*>(&S[XB + row * PAD + part * 4]) = ld[i];
    }
  }
  __syncthreads();

  // ---- conv branch q of row r ----
  const float* xr = &S[XB + r * PAD];
  float acc[5];
#pragma unroll
  for (int o = 0; o < 5; ++o) acc[o] = S[WB + 480 + q * 5 + o];
#pragma unroll
  for (int i = 0; i < 6; ++i) {
    float4 w4 = *reinterpret_cast<const float4*>(xr + 12 + 24 * q + 4 * i);
#pragma unroll
    for (int o = 0; o < 5; ++o) {
      float4 cw = *reinterpret_cast<const float4*>(&S[WB + q * 120 + o * 24 + 4 * i]);
      acc[o] = fmaf(w4.x, cw.x, acc[o]);
      acc[o] = fmaf(w4.y, cw.y, acc[o]);
      acc[o] = fmaf(w4.z, cw.z, acc[o]);
      acc[o] = fmaf(w4.w, cw.w, acc[o]);
    }
  }
#pragma unroll
  for (int o = 0; o < 5; ++o) S[CV + r * 24 + q * 5 + o] = fmaxf(acc[o], 0.f);
  __syncthreads();

  // ---- fc1 outputs o = q*5+j ----
  float h[5];
#pragma unroll
  for (int j = 0; j < 5; ++j) h[j] = S[WB + 1160 + q * 5 + j];
#pragma unroll
  for (int i = 0; i < 12; ++i) {
    float f = xr[i];
#pragma unroll
    for (int j = 0; j < 5; ++j)
      h[j] = fmaf(f, S[WB + 500 + (q * 5 + j) * 33 + i], h[j]);
  }
#pragma unroll
  for (int i = 12; i < 32; ++i) {
    float f = S[CV + r * 24 + (i - 12)];
#pragma unroll
    for (int j = 0; j < 5; ++j)
      h[j] = fmaf(f, S[WB + 500 + (q * 5 + j) * 33 + i], h[j]);
  }
#pragma unroll
  for (int j = 0; j < 5; ++j) h[j] = fmaxf(h[j], 0.f);

  // ---- coef partials over this thread's 5 h-values; reduce across q ----
  float pf[4];
#pragma unroll
  for (int f = 0; f < 4; ++f) {
    float s = 0.f;
#pragma unroll
    for (int j = 0; j < 5; ++j)
      s = fmaf(h[j], S[WB + 1180 + f * 20 + q * 5 + j], s);
    pf[f] = s;
  }
#pragma unroll
  for (int f = 0; f < 4; ++f) {
    pf[f] += __shfl_xor(pf[f], 1, 4);
    pf[f] += __shfl_xor(pf[f], 2, 4);
  }

  if (q == 0) {
    size_t rr = base + r;
    int b = (int)(rr / N);
    int n = (int)(rr - (size_t)b * N);
    float s0 = pf[0] + S[WB + 1180 + 80];
    float s1 = pf[1] + S[WB + 1180 + 81];
    float s2 = pf[2] + S[WB + 1180 + 82];
    float s3 = pf[3] + S[WB + 1180 + 83];
    F1v[n * 16 + b] = make_float2(s0, s1);
    F2v[n * 16 + b] = make_float2(s2, s3);
  }
}

// 16 lanes per node (one per batch); gather loop 4x unrolled (4 loads in flight).
__global__ void k_agg1(const int* __restrict__ row_ptr, const int* __restrict__ adj,
                       const float2* __restrict__ F1v, const float2* __restrict__ F2v,
                       float* __restrict__ W, float* __restrict__ V, int N) {
  int t = blockIdx.x * blockDim.x + threadIdx.x;
  int g = t >> 4, b = t & 15;
  if (g >= N) return;
  int beg = row_ptr[g], end = row_ptr[g + 1];
  float sa = 0.f, sb = 0.f;
  for (int c = beg; c < end; c += 16) {
    int idx = c + b;
    int a = adj[idx < end ? idx : end - 1];
    int m = min(16, end - c);
    int k = 0;
    for (; k + 4 <= m; k += 4) {
      int s0 = __shfl(a, k, 16),     s1 = __shfl(a, k + 1, 16);
      int s2 = __shfl(a, k + 2, 16), s3 = __shfl(a, k + 3, 16);
      float2 f0 = F1v[s0 * 16 + b], f1 = F1v[s1 * 16 + b];
      float2 f2 = F1v[s2 * 16 + b], f3 = F1v[s3 * 16 + b];
      sa += (f0.x + f1.x) + (f2.x + f3.x);
      sb += (f0.y + f1.y) + (f2.y + f3.y);
    }
    for (; k < m; ++k) {
      int s = __shfl(a, k, 16);
      float2 f = F1v[s * 16 + b];
      sa += f.x; sb += f.y;
    }
  }
  float inv = 1.0f / fmaxf((float)(end - beg), 1.0f);
  float2 f2v = F2v[t];
  W[t] = sa * inv + f2v.x;
  V[t] = sb * inv;
}

// second gather over W, fused with the final epilogue; LDS transpose so the
// out[b*N+n] write is coalesced per plane.
__global__ __launch_bounds__(256) void k_agg2(
    const int* __restrict__ row_ptr, const int* __restrict__ adj,
    const float* __restrict__ W, const float* __restrict__ V,
    const float2* __restrict__ F2v, const float* __restrict__ coef,
    const float* __restrict__ g2_bl, float* __restrict__ out, int N) {
  __shared__ float tile[16][17];
  int t = blockIdx.x * 256 + threadIdx.x;
  int g = t >> 4, b = t & 15;
  float r = 0.f;
  if (g < N) {
    int beg = row_ptr[g], end = row_ptr[g + 1];
    float sw = 0.f;
    for (int c = beg; c < end; c += 16) {
      int idx = c + b;
      int a = adj[idx < end ? idx : end - 1];
      int m = min(16, end - c);
      int k = 0;
      for (; k + 4 <= m; k += 4) {
        int s0 = __shfl(a, k, 16),     s1 = __shfl(a, k + 1, 16);
        int s2 = __shfl(a, k + 2, 16), s3 = __shfl(a, k + 3, 16);
        sw += (W[s0 * 16 + b] + W[s1 * 16 + b]) + (W[s2 * 16 + b] + W[s3 * 16 + b]);
      }
      for (; k < m; ++k) {
        int s = __shfl(a, k, 16);
        sw += W[s * 16 + b];
      }
    }
    int deg = end - beg;
    float inv = 1.0f / fmaxf((float)deg, 1.0f);
    float chi = deg > 0 ? 1.f : 0.f;
    r = sw * inv + V[t] + F2v[t].y + coef[84] * chi + coef[85] + g2_bl[0];
  }
  int gl = (threadIdx.x >> 4);
  tile[b][gl] = r;
  __syncthreads();
  int b2 = threadIdx.x >> 4;
  int gl2 = threadIdx.x & 15;
  int n2 = blockIdx.x * 16 + gl2;
  if (n2 < N) out[(size_t)b2 * N + n2] = tile[b2][gl2];
}

extern "C" void kernel_launch(void* const* d_in, const int* in_sizes, int n_in,
                              void* d_out, int out_size, void* d_ws, size_t ws_size,
                              hipStream_t stream) {
  const float* x     = (const float*)d_in[0];
  const int*   ei    = (const int*)d_in[1];
  const float* w_t   = (const float*)d_in[2];
  const float* b_t   = (const float*)d_in[3];
  const float* w_r   = (const float*)d_in[4];
  const float* b_r   = (const float*)d_in[5];
  const float* w_tp  = (const float*)d_in[6];
  const float* b_tp  = (const float*)d_in[7];
  const float* w_ssr = (const float*)d_in[8];
  const float* b_ssr = (const float*)d_in[9];
  const float* f1w   = (const float*)d_in[10];
  const float* f1b   = (const float*)d_in[11];
  const float* f2w   = (const float*)d_in[12];
  const float* f2b   = (const float*)d_in[13];
  const float* g1_wl = (const float*)d_in[14];
  const float* g1_bl = (const float*)d_in[15];
  const float* g1_wr = (const float*)d_in[16];
  const float* g2_wl = (const float*)d_in[17];
  const float* g2_bl = (const float*)d_in[18];
  const float* g2_wr = (const float*)d_in[19];
  float* out = (float*)d_out;

  const int E = in_sizes[1] / 2;
  const int N = out_size / 16;   // B = 16
  const int rows = out_size;     // N * B = 320000
  const int* src = ei;
  const int* dst = ei + E;

  // workspace
  float* ws  = (float*)d_ws;
  float2* F1v = (float2*)ws;                    // 16N float2
  float2* F2v = F1v + (size_t)16 * N;           // 16N float2
  float*  W   = (float*)(F2v + (size_t)16 * N); // 16N f32
  float*  V   = W + (size_t)16 * N;             // 16N f32
  float*  coef = V + (size_t)16 * N;            // 86
  int* cnt     = (int*)(coef + 128);            // N
  int* row_ptr = cnt + N;                       // N+1
  int* cursor  = row_ptr + N + 1;               // N
  int* adj     = cursor + N;                    // E

  int nb16 = (N * 16 + 255) / 256;

  k_zero<<<(N + 255) / 256, 256, 0, stream>>>(cnt, N);
  k_count<<<(E + 255) / 256, 256, 0, stream>>>(dst, E, cnt);
  k_scan<<<1, 1024, 0, stream>>>(cnt, N, row_ptr, cursor,
                                 f2w, f2b, g1_wl, g1_bl, g1_wr, g2_wl, g2_wr, coef);
  k_scatter<<<(E + 255) / 256, 256, 0, stream>>>(src, dst, E, cursor, adj);
  k_mlp<<<rows / 64, 256, 0, stream>>>(
      x, w_t, b_t, w_r, b_r, w_tp, b_tp, w_ssr, b_ssr,
      f1w, f1b, coef, F1v, F2v, N);
  k_agg1<<<nb16, 256, 0, stream>>>(row_ptr, adj, F1v, F2v, W, V, N);
  k_agg2<<<nb16, 256, 0, stream>>>(row_ptr, adj, W, V, F2v, coef, g2_bl, out, N);
}